// Round 1
// baseline (1462.488 us; speedup 1.0000x reference)
//
#include <hip/hip_runtime.h>

#define N_NODES 100000
#define N_EDGES 1600000
#define D 128            // D_IN == D_HID == D_OUT == 128
#define TILE_N 64        // nodes per GEMM block
#define LDS_S 260        // 256 concat dims + 4 pad floats (bank spread, keeps 16B align)

// ---------------- CSR build ----------------

__global__ __launch_bounds__(256) void hist_kernel(const int* __restrict__ dst,
                                                   int* __restrict__ cnt, int n) {
    int i = blockIdx.x * blockDim.x + threadIdx.x;
    if (i < n) atomicAdd(&cnt[dst[i]], 1);
}

// single-block exclusive scan over 100K counts -> row_ptr[0..N], row_ptr[N]=E
__global__ __launch_bounds__(1024) void scan_kernel(const int* __restrict__ cnt,
                                                    int* __restrict__ row_ptr, int n) {
    __shared__ int sums[1024];
    int tid = threadIdx.x;
    int chunk = (n + 1023) >> 10;           // 98
    int beg = tid * chunk;
    int end = min(beg + chunk, n);
    int s = 0;
    for (int i = beg; i < end; ++i) s += cnt[i];
    sums[tid] = s;
    __syncthreads();
    // Hillis-Steele inclusive scan
    for (int off = 1; off < 1024; off <<= 1) {
        int v = (tid >= off) ? sums[tid - off] : 0;
        __syncthreads();
        sums[tid] += v;
        __syncthreads();
    }
    int run = (tid > 0) ? sums[tid - 1] : 0; // exclusive prefix of this chunk
    for (int i = beg; i < end; ++i) { row_ptr[i] = run; run += cnt[i]; }
    if (tid == 1023) row_ptr[n] = sums[1023];
}

__global__ __launch_bounds__(256) void scatter_kernel(const int* __restrict__ src,
                                                      const int* __restrict__ dst,
                                                      const int* __restrict__ row_ptr,
                                                      int* __restrict__ cursor,
                                                      int* __restrict__ sorted_src, int n) {
    int i = blockIdx.x * blockDim.x + threadIdx.x;
    if (i < n) {
        int d = dst[i];
        int p = atomicAdd(&cursor[d], 1);
        sorted_src[row_ptr[d] + p] = src[i];
    }
}

// ---------------- mean aggregation: one wave per node ----------------
// agg[i] = mean over incoming neighbors of h[src]

__global__ __launch_bounds__(256) void aggregate_kernel(const float* __restrict__ h,
                                                        const int* __restrict__ row_ptr,
                                                        const int* __restrict__ sorted_src,
                                                        float* __restrict__ agg) {
    int wid = (blockIdx.x * blockDim.x + threadIdx.x) >> 6;
    int lane = threadIdx.x & 63;
    if (wid >= N_NODES) return;
    int beg = row_ptr[wid], end = row_ptr[wid + 1];
    float2 acc = make_float2(0.f, 0.f);
    int j = beg;
    // 4-deep unroll for memory-level parallelism
    for (; j + 3 < end; j += 4) {
        int s0 = sorted_src[j], s1 = sorted_src[j + 1];
        int s2 = sorted_src[j + 2], s3 = sorted_src[j + 3];
        float2 v0 = *reinterpret_cast<const float2*>(h + (size_t)s0 * D + lane * 2);
        float2 v1 = *reinterpret_cast<const float2*>(h + (size_t)s1 * D + lane * 2);
        float2 v2 = *reinterpret_cast<const float2*>(h + (size_t)s2 * D + lane * 2);
        float2 v3 = *reinterpret_cast<const float2*>(h + (size_t)s3 * D + lane * 2);
        acc.x += v0.x + v1.x + v2.x + v3.x;
        acc.y += v0.y + v1.y + v2.y + v3.y;
    }
    for (; j < end; ++j) {
        int s = sorted_src[j];
        float2 v = *reinterpret_cast<const float2*>(h + (size_t)s * D + lane * 2);
        acc.x += v.x; acc.y += v.y;
    }
    float inv = 1.0f / (float)max(end - beg, 1);
    *reinterpret_cast<float2*>(agg + (size_t)wid * D + lane * 2) =
        make_float2(acc.x * inv, acc.y * inv);
}

// ---------------- fused dual GEMM + bias + ReLU ----------------
// out[i,:] = relu?( agg[i,:] @ Wl^T + bl + h[i,:] @ Wr^T )
// concat k-dim: k<128 -> (agg, Wl), k>=128 -> (h, Wr)

__global__ __launch_bounds__(256) void sage_gemm(const float* __restrict__ hin,
                                                 const float* __restrict__ agg,
                                                 const float* __restrict__ Wl,
                                                 const float* __restrict__ Wr,
                                                 const float* __restrict__ bl,
                                                 float* __restrict__ out, int relu) {
    __shared__ float in_lds[TILE_N * LDS_S];   // 66,560 B -> 2 blocks/CU
    int tid = threadIdx.x;
    int node0 = blockIdx.x * TILE_N;

    // stage 64 node rows: [agg(128) | h(128)] per row, coalesced full-row loads
    for (int idx = tid; idx < TILE_N * 64; idx += 256) {
        int r = idx >> 6, c4 = idx & 63;
        int node = node0 + r;
        float4 v = make_float4(0.f, 0.f, 0.f, 0.f);
        if (node < N_NODES) {
            if (c4 < 32) v = reinterpret_cast<const float4*>(agg + (size_t)node * D)[c4];
            else         v = reinterpret_cast<const float4*>(hin + (size_t)node * D)[c4 - 32];
        }
        *reinterpret_cast<float4*>(&in_lds[r * LDS_S + c4 * 4]) = v;
    }
    __syncthreads();

    int oq = tid & 31;       // output quad: o = oq*4
    int nq0 = tid >> 5;      // node quad base: nq in {nq0, nq0+8}
    int o = oq * 4;

    float4 acc[2][4];
    #pragma unroll
    for (int p = 0; p < 2; ++p)
        #pragma unroll
        for (int j = 0; j < 4; ++j) acc[p][j] = make_float4(0.f, 0.f, 0.f, 0.f);

    #pragma unroll 4
    for (int k4 = 0; k4 < 64; ++k4) {
        int k = k4 * 4;
        const float* Wbase = (k < 128) ? (Wl + k) : (Wr + (k - 128));
        float4 w0 = *reinterpret_cast<const float4*>(Wbase + (size_t)(o + 0) * D);
        float4 w1 = *reinterpret_cast<const float4*>(Wbase + (size_t)(o + 1) * D);
        float4 w2 = *reinterpret_cast<const float4*>(Wbase + (size_t)(o + 2) * D);
        float4 w3 = *reinterpret_cast<const float4*>(Wbase + (size_t)(o + 3) * D);
        #pragma unroll
        for (int p = 0; p < 2; ++p) {
            int nq = nq0 + p * 8;
            #pragma unroll
            for (int j = 0; j < 4; ++j) {
                int n = nq * 4 + j;
                float4 iv = *reinterpret_cast<const float4*>(&in_lds[n * LDS_S + k]);
                acc[p][j].x += iv.x * w0.x + iv.y * w0.y + iv.z * w0.z + iv.w * w0.w;
                acc[p][j].y += iv.x * w1.x + iv.y * w1.y + iv.z * w1.z + iv.w * w1.w;
                acc[p][j].z += iv.x * w2.x + iv.y * w2.y + iv.z * w2.z + iv.w * w2.w;
                acc[p][j].w += iv.x * w3.x + iv.y * w3.y + iv.z * w3.z + iv.w * w3.w;
            }
        }
    }

    float4 bias = *reinterpret_cast<const float4*>(bl + o);
    #pragma unroll
    for (int p = 0; p < 2; ++p) {
        int nq = nq0 + p * 8;
        #pragma unroll
        for (int j = 0; j < 4; ++j) {
            int node = node0 + nq * 4 + j;
            if (node >= N_NODES) continue;
            float4 r = acc[p][j];
            r.x += bias.x; r.y += bias.y; r.z += bias.z; r.w += bias.w;
            if (relu) {
                r.x = fmaxf(r.x, 0.f); r.y = fmaxf(r.y, 0.f);
                r.z = fmaxf(r.z, 0.f); r.w = fmaxf(r.w, 0.f);
            }
            *reinterpret_cast<float4*>(out + (size_t)node * D + o) = r;
        }
    }
}

// ---------------- launch ----------------

extern "C" void kernel_launch(void* const* d_in, const int* in_sizes, int n_in,
                              void* d_out, int out_size, void* d_ws, size_t ws_size,
                              hipStream_t stream) {
    const float* x   = (const float*)d_in[0];
    const int*   src = (const int*)d_in[1];
    const int*   dst = (const int*)d_in[2];
    const float* Wl0 = (const float*)d_in[3];
    const float* bl0 = (const float*)d_in[4];
    const float* Wr0 = (const float*)d_in[5];
    const float* Wl1 = (const float*)d_in[6];
    const float* bl1 = (const float*)d_in[7];
    const float* Wr1 = (const float*)d_in[8];
    const float* Wl2 = (const float*)d_in[9];
    const float* bl2 = (const float*)d_in[10];
    const float* Wr2 = (const float*)d_in[11];
    float* out = (float*)d_out;

    // workspace layout (total ~58.4 MB)
    int* cnt        = (int*)d_ws;                 // 100032 ints (also reused as cursor)
    int* row_ptr    = cnt + 100032;               // 100001 ints
    int* sorted_src = row_ptr + 100032;           // 1.6M ints
    float* agg      = (float*)((char*)d_ws + 7200256); // 51.2 MB, 512B-aligned

    const int EB = (N_EDGES + 255) / 256;         // 6250
    const int GB = (N_NODES + TILE_N - 1) / TILE_N; // 1563
    const int AB = (N_NODES * 64 + 255) / 256;    // 25000 (one wave per node)

    // CSR build (once; reused by all 3 layers)
    hipMemsetAsync(cnt, 0, N_NODES * sizeof(int), stream);
    hist_kernel<<<EB, 256, 0, stream>>>(dst, cnt, N_EDGES);
    scan_kernel<<<1, 1024, 0, stream>>>(cnt, row_ptr, N_NODES);
    hipMemsetAsync(cnt, 0, N_NODES * sizeof(int), stream);  // reuse as cursor
    scatter_kernel<<<EB, 256, 0, stream>>>(src, dst, row_ptr, cnt, sorted_src, N_EDGES);

    // layer 0: x -> out (ReLU)
    aggregate_kernel<<<AB, 256, 0, stream>>>(x, row_ptr, sorted_src, agg);
    sage_gemm<<<GB, 256, 0, stream>>>(x, agg, Wl0, Wr0, bl0, out, 1);
    // layer 1: out -> out (ReLU), in-place safe (row i reads only row i after agg)
    aggregate_kernel<<<AB, 256, 0, stream>>>(out, row_ptr, sorted_src, agg);
    sage_gemm<<<GB, 256, 0, stream>>>(out, agg, Wl1, Wr1, bl1, out, 1);
    // layer 2: out -> out (no ReLU)
    aggregate_kernel<<<AB, 256, 0, stream>>>(out, row_ptr, sorted_src, agg);
    sage_gemm<<<GB, 256, 0, stream>>>(out, agg, Wl2, Wr2, bl2, out, 0);
}

// Round 2
// 1105.467 us; speedup vs baseline: 1.3230x; 1.3230x over previous
//
#include <hip/hip_runtime.h>

#define N_NODES 100000
#define N_EDGES 1600000
#define D 128            // D_IN == D_HID == D_OUT == 128
#define TILE_N 64        // nodes per GEMM block

// ---------------- CSR build ----------------

__global__ __launch_bounds__(256) void hist_kernel(const int* __restrict__ dst,
                                                   int* __restrict__ cnt, int n) {
    int i = blockIdx.x * blockDim.x + threadIdx.x;
    if (i < n) atomicAdd(&cnt[dst[i]], 1);
}

// single-block exclusive scan over 100K counts -> row_ptr[0..N], row_ptr[N]=E
__global__ __launch_bounds__(1024) void scan_kernel(const int* __restrict__ cnt,
                                                    int* __restrict__ row_ptr, int n) {
    __shared__ int sums[1024];
    int tid = threadIdx.x;
    int chunk = (n + 1023) >> 10;           // 98
    int beg = tid * chunk;
    int end = min(beg + chunk, n);
    int s = 0;
    for (int i = beg; i < end; ++i) s += cnt[i];
    sums[tid] = s;
    __syncthreads();
    for (int off = 1; off < 1024; off <<= 1) {
        int v = (tid >= off) ? sums[tid - off] : 0;
        __syncthreads();
        sums[tid] += v;
        __syncthreads();
    }
    int run = (tid > 0) ? sums[tid - 1] : 0;
    for (int i = beg; i < end; ++i) { row_ptr[i] = run; run += cnt[i]; }
    if (tid == 1023) row_ptr[n] = sums[1023];
}

__global__ __launch_bounds__(256) void scatter_kernel(const int* __restrict__ src,
                                                      const int* __restrict__ dst,
                                                      const int* __restrict__ row_ptr,
                                                      int* __restrict__ cursor,
                                                      int* __restrict__ sorted_src, int n) {
    int i = blockIdx.x * blockDim.x + threadIdx.x;
    if (i < n) {
        int d = dst[i];
        int p = atomicAdd(&cursor[d], 1);
        sorted_src[row_ptr[d] + p] = src[i];
    }
}

// ---------------- W transpose: Wt[k][o] = concat(Wl,Wr)[o][k] ----------------

__global__ __launch_bounds__(256) void transpose_w(const float* __restrict__ Wl,
                                                   const float* __restrict__ Wr,
                                                   float* __restrict__ Wt) {
    int i = blockIdx.x * 256 + threadIdx.x;   // 256*128 = 32768
    if (i >= 256 * 128) return;
    int k = i >> 7, o = i & 127;
    Wt[i] = (k < 128) ? Wl[o * 128 + k] : Wr[o * 128 + (k - 128)];
}

// ---------------- mean aggregation: one wave per node, 2 edges per load ----------------

__global__ __launch_bounds__(256) void aggregate_kernel(const float* __restrict__ h,
                                                        const int* __restrict__ row_ptr,
                                                        const int* __restrict__ sorted_src,
                                                        float* __restrict__ agg) {
    int wid = (blockIdx.x * blockDim.x + threadIdx.x) >> 6;
    int lane = threadIdx.x & 63;
    int half = lane >> 5;        // 0: even edge of pair, 1: odd edge
    int l32 = lane & 31;         // float4 slot within the 128-float row
    if (wid >= N_NODES) return;
    int beg = row_ptr[wid], end = row_ptr[wid + 1];
    int deg = end - beg;
    float4 acc = make_float4(0.f, 0.f, 0.f, 0.f);
    int j = beg;
    int end8 = beg + (deg & ~7);
    for (; j < end8; j += 8) {   // 8 edges per iter, 4 gathers in flight per lane
        int s0 = sorted_src[j + 0 + half];
        int s1 = sorted_src[j + 2 + half];
        int s2 = sorted_src[j + 4 + half];
        int s3 = sorted_src[j + 6 + half];
        float4 v0 = *reinterpret_cast<const float4*>(h + (size_t)s0 * D + l32 * 4);
        float4 v1 = *reinterpret_cast<const float4*>(h + (size_t)s1 * D + l32 * 4);
        float4 v2 = *reinterpret_cast<const float4*>(h + (size_t)s2 * D + l32 * 4);
        float4 v3 = *reinterpret_cast<const float4*>(h + (size_t)s3 * D + l32 * 4);
        acc.x += v0.x + v1.x + v2.x + v3.x;
        acc.y += v0.y + v1.y + v2.y + v3.y;
        acc.z += v0.z + v1.z + v2.z + v3.z;
        acc.w += v0.w + v1.w + v2.w + v3.w;
    }
    for (; j < end; j += 2) {    // tail: up to 7 edges, pairs
        int e = j + half;
        if (e < end) {
            int s = sorted_src[e];
            float4 v = *reinterpret_cast<const float4*>(h + (size_t)s * D + l32 * 4);
            acc.x += v.x; acc.y += v.y; acc.z += v.z; acc.w += v.w;
        }
    }
    // combine the two halves (edge-parity partial sums)
    acc.x += __shfl_xor(acc.x, 32, 64);
    acc.y += __shfl_xor(acc.y, 32, 64);
    acc.z += __shfl_xor(acc.z, 32, 64);
    acc.w += __shfl_xor(acc.w, 32, 64);
    float inv = 1.0f / (float)max(deg, 1);
    if (half == 0)
        *reinterpret_cast<float4*>(agg + (size_t)wid * D + l32 * 4) =
            make_float4(acc.x * inv, acc.y * inv, acc.z * inv, acc.w * inv);
}

// ---------------- fused dual GEMM + bias + ReLU (W^T coalesced) ----------------
// out[i,:] = relu?( [agg(i)|h(i)] @ Wt + bl )

__global__ __launch_bounds__(256) void sage_gemm(const float* __restrict__ hin,
                                                 const float* __restrict__ agg,
                                                 const float* __restrict__ Wt,  // [256][128]
                                                 const float* __restrict__ bl,
                                                 float* __restrict__ out, int relu) {
    __shared__ float in_lds[TILE_N * 256];   // 65536 B -> 2 blocks/CU
    int tid = threadIdx.x;
    int node0 = blockIdx.x * TILE_N;

    // stage 64 node rows: [agg(128) | h(128)] per row, coalesced float4 loads
    for (int idx = tid; idx < TILE_N * 64; idx += 256) {
        int r = idx >> 6, c4 = idx & 63;
        int node = node0 + r;
        float4 v = make_float4(0.f, 0.f, 0.f, 0.f);
        if (node < N_NODES) {
            if (c4 < 32) v = reinterpret_cast<const float4*>(agg + (size_t)node * D)[c4];
            else         v = reinterpret_cast<const float4*>(hin + (size_t)node * D)[c4 - 32];
        }
        *reinterpret_cast<float4*>(&in_lds[r * 256 + c4 * 4]) = v;
    }
    __syncthreads();

    int o  = (tid & 31) * 4;   // 4 output cols per thread
    int ng = tid >> 5;         // node sub-index 0..7; 8 nodes per thread
    float4 acc[8];
    #pragma unroll
    for (int j = 0; j < 8; ++j) acc[j] = make_float4(0.f, 0.f, 0.f, 0.f);

    #pragma unroll 2
    for (int k4 = 0; k4 < 64; ++k4) {
        int k = k4 * 4;
        // coalesced: lanes 0-31 read 512 consecutive bytes; 32-63 broadcast same lines
        float4 w0 = *reinterpret_cast<const float4*>(Wt + (size_t)(k + 0) * 128 + o);
        float4 w1 = *reinterpret_cast<const float4*>(Wt + (size_t)(k + 1) * 128 + o);
        float4 w2 = *reinterpret_cast<const float4*>(Wt + (size_t)(k + 2) * 128 + o);
        float4 w3 = *reinterpret_cast<const float4*>(Wt + (size_t)(k + 3) * 128 + o);
        #pragma unroll
        for (int j = 0; j < 8; ++j) {
            int n = j * 8 + ng;
            float4 iv = *reinterpret_cast<const float4*>(&in_lds[n * 256 + k]); // half-wave broadcast
            acc[j].x += iv.x * w0.x + iv.y * w1.x + iv.z * w2.x + iv.w * w3.x;
            acc[j].y += iv.x * w0.y + iv.y * w1.y + iv.z * w2.y + iv.w * w3.y;
            acc[j].z += iv.x * w0.z + iv.y * w1.z + iv.z * w2.z + iv.w * w3.z;
            acc[j].w += iv.x * w0.w + iv.y * w1.w + iv.z * w2.w + iv.w * w3.w;
        }
    }

    float4 bias = *reinterpret_cast<const float4*>(bl + o);
    #pragma unroll
    for (int j = 0; j < 8; ++j) {
        int node = node0 + j * 8 + ng;
        if (node >= N_NODES) continue;
        float4 r = acc[j];
        r.x += bias.x; r.y += bias.y; r.z += bias.z; r.w += bias.w;
        if (relu) {
            r.x = fmaxf(r.x, 0.f); r.y = fmaxf(r.y, 0.f);
            r.z = fmaxf(r.z, 0.f); r.w = fmaxf(r.w, 0.f);
        }
        *reinterpret_cast<float4*>(out + (size_t)node * D + o) = r;  // coalesced
    }
}

// ---------------- launch ----------------

extern "C" void kernel_launch(void* const* d_in, const int* in_sizes, int n_in,
                              void* d_out, int out_size, void* d_ws, size_t ws_size,
                              hipStream_t stream) {
    const float* x   = (const float*)d_in[0];
    const int*   src = (const int*)d_in[1];
    const int*   dst = (const int*)d_in[2];
    const float* Wl0 = (const float*)d_in[3];
    const float* bl0 = (const float*)d_in[4];
    const float* Wr0 = (const float*)d_in[5];
    const float* Wl1 = (const float*)d_in[6];
    const float* bl1 = (const float*)d_in[7];
    const float* Wr1 = (const float*)d_in[8];
    const float* Wl2 = (const float*)d_in[9];
    const float* bl2 = (const float*)d_in[10];
    const float* Wr2 = (const float*)d_in[11];
    float* out = (float*)d_out;

    // workspace layout (~58.8 MB)
    int* cnt        = (int*)d_ws;                        // 100032 ints (reused as cursor)
    int* row_ptr    = cnt + 100032;                      // 100001 ints
    int* sorted_src = row_ptr + 100032;                  // 1.6M ints
    float* Wt0      = (float*)((char*)d_ws + 7200256);   // 3 x 32768 floats
    float* Wt1      = Wt0 + 32768;
    float* Wt2      = Wt1 + 32768;
    float* agg      = (float*)((char*)d_ws + 7593472);   // 51.2 MB

    const int EB = (N_EDGES + 255) / 256;                // 6250
    const int GB = (N_NODES + TILE_N - 1) / TILE_N;      // 1563
    const int AB = (N_NODES * 64 + 255) / 256;           // 25000 (one wave per node)
    const int TB = (256 * 128 + 255) / 256;              // 128

    // CSR build (once; reused by all 3 layers)
    hipMemsetAsync(cnt, 0, N_NODES * sizeof(int), stream);
    hist_kernel<<<EB, 256, 0, stream>>>(dst, cnt, N_EDGES);
    scan_kernel<<<1, 1024, 0, stream>>>(cnt, row_ptr, N_NODES);
    hipMemsetAsync(cnt, 0, N_NODES * sizeof(int), stream);
    scatter_kernel<<<EB, 256, 0, stream>>>(src, dst, row_ptr, cnt, sorted_src, N_EDGES);

    // W transposes (tiny, one-time per call)
    transpose_w<<<TB, 256, 0, stream>>>(Wl0, Wr0, Wt0);
    transpose_w<<<TB, 256, 0, stream>>>(Wl1, Wr1, Wt1);
    transpose_w<<<TB, 256, 0, stream>>>(Wl2, Wr2, Wt2);

    // layer 0: x -> out (ReLU)
    aggregate_kernel<<<AB, 256, 0, stream>>>(x, row_ptr, sorted_src, agg);
    sage_gemm<<<GB, 256, 0, stream>>>(x, agg, Wt0, bl0, out, 1);
    // layer 1: out -> out (ReLU); in-place safe (GEMM row i reads only row i)
    aggregate_kernel<<<AB, 256, 0, stream>>>(out, row_ptr, sorted_src, agg);
    sage_gemm<<<GB, 256, 0, stream>>>(out, agg, Wt1, bl1, out, 1);
    // layer 2: out -> out (no ReLU)
    aggregate_kernel<<<AB, 256, 0, stream>>>(out, row_ptr, sorted_src, agg);
    sage_gemm<<<GB, 256, 0, stream>>>(out, agg, Wt2, bl2, out, 0);
}

// Round 4
// 973.540 us; speedup vs baseline: 1.5022x; 1.1355x over previous
//
#include <hip/hip_runtime.h>

#define N_NODES 100000
#define N_EDGES 1600000
#define D 128            // D_IN == D_HID == D_OUT == 128
#define TILE_N 32        // nodes per GEMM block (32 KB LDS -> ~5 blocks/CU)
#define NBS 98           // scan blocks: ceil(100000/1024)

// ---------------- CSR build ----------------

__global__ __launch_bounds__(256) void hist_kernel(const int* __restrict__ dst,
                                                   int* __restrict__ cnt, int n) {
    int i = blockIdx.x * blockDim.x + threadIdx.x;
    if (i < n) atomicAdd(&cnt[dst[i]], 1);
}

// pass 1: per-block (1024 counts) reduce -> bsum[b]
__global__ __launch_bounds__(256) void scan_reduce(const int* __restrict__ cnt,
                                                   int* __restrict__ bsum, int n) {
    __shared__ int s[4];
    int b = blockIdx.x, t = threadIdx.x;
    int base = b * 1024;
    int v = 0;
    for (int q = 0; q < 4; ++q) {
        int i = base + q * 256 + t;
        if (i < n) v += cnt[i];
    }
    // wave reduce
    for (int off = 32; off > 0; off >>= 1) v += __shfl_down(v, off, 64);
    if ((t & 63) == 0) s[t >> 6] = v;
    __syncthreads();
    if (t == 0) bsum[b] = s[0] + s[1] + s[2] + s[3];
}

// pass 2: single small block scans the 98 block sums -> exclusive bpre[b]
__global__ __launch_bounds__(128) void scan_partials(const int* __restrict__ bsum,
                                                     int* __restrict__ bpre) {
    __shared__ int s[128];
    int t = threadIdx.x;
    int v = (t < NBS) ? bsum[t] : 0;
    s[t] = v;
    __syncthreads();
    for (int off = 1; off < 128; off <<= 1) {
        int u = (t >= off) ? s[t - off] : 0;
        __syncthreads();
        s[t] += u;
        __syncthreads();
    }
    if (t < NBS) bpre[t] = s[t] - v;   // exclusive
}

// pass 3: per-block 1024-wide exclusive scan + block offset -> row_ptr
__global__ __launch_bounds__(1024) void scan_write(const int* __restrict__ cnt,
                                                   const int* __restrict__ bpre,
                                                   int* __restrict__ row_ptr, int n) {
    __shared__ int s[1024];
    int b = blockIdx.x, t = threadIdx.x;
    int i = b * 1024 + t;
    int c = (i < n) ? cnt[i] : 0;
    s[t] = c;
    __syncthreads();
    for (int off = 1; off < 1024; off <<= 1) {
        int u = (t >= off) ? s[t - off] : 0;
        __syncthreads();
        s[t] += u;
        __syncthreads();
    }
    if (i < n) row_ptr[i] = bpre[b] + s[t] - c;
    if (b == 0 && t == 0) row_ptr[n] = N_EDGES;
}

__global__ __launch_bounds__(256) void scatter_kernel(const int* __restrict__ src,
                                                      const int* __restrict__ dst,
                                                      const int* __restrict__ row_ptr,
                                                      int* __restrict__ cursor,
                                                      int* __restrict__ sorted_src, int n) {
    int i = blockIdx.x * blockDim.x + threadIdx.x;
    if (i < n) {
        int d = dst[i];
        int p = atomicAdd(&cursor[d], 1);
        sorted_src[row_ptr[d] + p] = src[i];
    }
}

// ---------------- W transpose: Wt[k][o] = concat(Wl,Wr)[o][k] ----------------

__global__ __launch_bounds__(256) void transpose_w(const float* __restrict__ Wl,
                                                   const float* __restrict__ Wr,
                                                   float* __restrict__ Wt) {
    int i = blockIdx.x * 256 + threadIdx.x;   // 256*128 = 32768
    if (i >= 256 * 128) return;
    int k = i >> 7, o = i & 127;
    Wt[i] = (k < 128) ? Wl[o * 128 + k] : Wr[o * 128 + (k - 128)];
}

// ---------------- mean aggregation: one wave per node, deep MLP ----------------

__global__ __launch_bounds__(256) void aggregate_kernel(const float* __restrict__ h,
                                                        const int* __restrict__ row_ptr,
                                                        const int* __restrict__ sorted_src,
                                                        float* __restrict__ agg) {
    int wid = (blockIdx.x * blockDim.x + threadIdx.x) >> 6;
    int lane = threadIdx.x & 63;
    int half = lane >> 5;        // 0: even edge of pair, 1: odd edge
    int l32 = lane & 31;         // float4 slot within the 128-float row
    if (wid >= N_NODES) return;
    int beg = row_ptr[wid], end = row_ptr[wid + 1];
    int deg = end - beg;
    float4 acc = make_float4(0.f, 0.f, 0.f, 0.f);
    int j = beg;
    int end16 = beg + (deg & ~15);
    for (; j < end16; j += 16) {  // 16 edges per iter, 8 gathers in flight per lane
        int s0 = sorted_src[j +  0 + half];
        int s1 = sorted_src[j +  2 + half];
        int s2 = sorted_src[j +  4 + half];
        int s3 = sorted_src[j +  6 + half];
        int s4 = sorted_src[j +  8 + half];
        int s5 = sorted_src[j + 10 + half];
        int s6 = sorted_src[j + 12 + half];
        int s7 = sorted_src[j + 14 + half];
        float4 v0 = *reinterpret_cast<const float4*>(h + (size_t)s0 * D + l32 * 4);
        float4 v1 = *reinterpret_cast<const float4*>(h + (size_t)s1 * D + l32 * 4);
        float4 v2 = *reinterpret_cast<const float4*>(h + (size_t)s2 * D + l32 * 4);
        float4 v3 = *reinterpret_cast<const float4*>(h + (size_t)s3 * D + l32 * 4);
        float4 v4 = *reinterpret_cast<const float4*>(h + (size_t)s4 * D + l32 * 4);
        float4 v5 = *reinterpret_cast<const float4*>(h + (size_t)s5 * D + l32 * 4);
        float4 v6 = *reinterpret_cast<const float4*>(h + (size_t)s6 * D + l32 * 4);
        float4 v7 = *reinterpret_cast<const float4*>(h + (size_t)s7 * D + l32 * 4);
        acc.x += (v0.x + v1.x) + (v2.x + v3.x) + ((v4.x + v5.x) + (v6.x + v7.x));
        acc.y += (v0.y + v1.y) + (v2.y + v3.y) + ((v4.y + v5.y) + (v6.y + v7.y));
        acc.z += (v0.z + v1.z) + (v2.z + v3.z) + ((v4.z + v5.z) + (v6.z + v7.z));
        acc.w += (v0.w + v1.w) + (v2.w + v3.w) + ((v4.w + v5.w) + (v6.w + v7.w));
    }
    for (; j + 7 < end; j += 8) {
        int s0 = sorted_src[j + 0 + half];
        int s1 = sorted_src[j + 2 + half];
        int s2 = sorted_src[j + 4 + half];
        int s3 = sorted_src[j + 6 + half];
        float4 v0 = *reinterpret_cast<const float4*>(h + (size_t)s0 * D + l32 * 4);
        float4 v1 = *reinterpret_cast<const float4*>(h + (size_t)s1 * D + l32 * 4);
        float4 v2 = *reinterpret_cast<const float4*>(h + (size_t)s2 * D + l32 * 4);
        float4 v3 = *reinterpret_cast<const float4*>(h + (size_t)s3 * D + l32 * 4);
        acc.x += (v0.x + v1.x) + (v2.x + v3.x);
        acc.y += (v0.y + v1.y) + (v2.y + v3.y);
        acc.z += (v0.z + v1.z) + (v2.z + v3.z);
        acc.w += (v0.w + v1.w) + (v2.w + v3.w);
    }
    for (; j < end; j += 2) {
        int e = j + half;
        if (e < end) {
            int s = sorted_src[e];
            float4 v = *reinterpret_cast<const float4*>(h + (size_t)s * D + l32 * 4);
            acc.x += v.x; acc.y += v.y; acc.z += v.z; acc.w += v.w;
        }
    }
    acc.x += __shfl_xor(acc.x, 32, 64);
    acc.y += __shfl_xor(acc.y, 32, 64);
    acc.z += __shfl_xor(acc.z, 32, 64);
    acc.w += __shfl_xor(acc.w, 32, 64);
    float inv = 1.0f / (float)max(deg, 1);
    if (half == 0)
        *reinterpret_cast<float4*>(agg + (size_t)wid * D + l32 * 4) =
            make_float4(acc.x * inv, acc.y * inv, acc.z * inv, acc.w * inv);
}

// ---------------- fused dual GEMM + bias + ReLU (W^T coalesced) ----------------
// out[i,:] = relu?( [agg(i)|h(i)] @ Wt + bl )

__global__ __launch_bounds__(256) void sage_gemm(const float* __restrict__ hin,
                                                 const float* __restrict__ agg,
                                                 const float* __restrict__ Wt,  // [256][128]
                                                 const float* __restrict__ bl,
                                                 float* __restrict__ out, int relu) {
    __shared__ float in_lds[TILE_N * 256];   // 32768 B -> ~5 blocks/CU
    int tid = threadIdx.x;
    int node0 = blockIdx.x * TILE_N;

    // stage 32 node rows: [agg(128) | h(128)] per row, coalesced float4 loads
    for (int idx = tid; idx < TILE_N * 64; idx += 256) {
        int r = idx >> 6, c4 = idx & 63;
        int node = node0 + r;
        float4 v = make_float4(0.f, 0.f, 0.f, 0.f);
        if (node < N_NODES) {
            if (c4 < 32) v = reinterpret_cast<const float4*>(agg + (size_t)node * D)[c4];
            else         v = reinterpret_cast<const float4*>(hin + (size_t)node * D)[c4 - 32];
        }
        *reinterpret_cast<float4*>(&in_lds[r * 256 + c4 * 4]) = v;
    }
    __syncthreads();

    int o  = (tid & 31) * 4;   // 4 output cols per thread
    int ng = tid >> 5;         // node sub-index 0..7; 4 nodes per thread
    float4 acc[4];
    #pragma unroll
    for (int j = 0; j < 4; ++j) acc[j] = make_float4(0.f, 0.f, 0.f, 0.f);

    #pragma unroll 2
    for (int k4 = 0; k4 < 64; ++k4) {
        int k = k4 * 4;
        // coalesced: lanes 0-31 read 512 consecutive bytes; 32-63 hit same lines
        float4 w0 = *reinterpret_cast<const float4*>(Wt + (size_t)(k + 0) * 128 + o);
        float4 w1 = *reinterpret_cast<const float4*>(Wt + (size_t)(k + 1) * 128 + o);
        float4 w2 = *reinterpret_cast<const float4*>(Wt + (size_t)(k + 2) * 128 + o);
        float4 w3 = *reinterpret_cast<const float4*>(Wt + (size_t)(k + 3) * 128 + o);
        #pragma unroll
        for (int j = 0; j < 4; ++j) {
            int n = j * 8 + ng;
            float4 iv = *reinterpret_cast<const float4*>(&in_lds[n * 256 + k]); // 2-addr broadcast
            acc[j].x += iv.x * w0.x + iv.y * w1.x + iv.z * w2.x + iv.w * w3.x;
            acc[j].y += iv.x * w0.y + iv.y * w1.y + iv.z * w2.y + iv.w * w3.y;
            acc[j].z += iv.x * w0.z + iv.y * w1.z + iv.z * w2.z + iv.w * w3.z;
            acc[j].w += iv.x * w0.w + iv.y * w1.w + iv.z * w2.w + iv.w * w3.w;
        }
    }

    float4 bias = *reinterpret_cast<const float4*>(bl + o);
    #pragma unroll
    for (int j = 0; j < 4; ++j) {
        int node = node0 + j * 8 + ng;
        if (node >= N_NODES) continue;
        float4 r = acc[j];
        r.x += bias.x; r.y += bias.y; r.z += bias.z; r.w += bias.w;
        if (relu) {
            r.x = fmaxf(r.x, 0.f); r.y = fmaxf(r.y, 0.f);
            r.z = fmaxf(r.z, 0.f); r.w = fmaxf(r.w, 0.f);
        }
        *reinterpret_cast<float4*>(out + (size_t)node * D + o) = r;  // coalesced
    }
}

// ---------------- launch ----------------

extern "C" void kernel_launch(void* const* d_in, const int* in_sizes, int n_in,
                              void* d_out, int out_size, void* d_ws, size_t ws_size,
                              hipStream_t stream) {
    const float* x   = (const float*)d_in[0];
    const int*   src = (const int*)d_in[1];
    const int*   dst = (const int*)d_in[2];
    const float* Wl0 = (const float*)d_in[3];
    const float* bl0 = (const float*)d_in[4];
    const float* Wr0 = (const float*)d_in[5];
    const float* Wl1 = (const float*)d_in[6];
    const float* bl1 = (const float*)d_in[7];
    const float* Wr1 = (const float*)d_in[8];
    const float* Wl2 = (const float*)d_in[9];
    const float* bl2 = (const float*)d_in[10];
    const float* Wr2 = (const float*)d_in[11];
    float* out = (float*)d_out;

    // workspace layout (~58.8 MB), unchanged from R1
    int* cnt        = (int*)d_ws;                        // 100032 ints (reused as cursor)
    int* row_ptr    = cnt + 100032;                      // 100001 ints
    int* sorted_src = row_ptr + 100032;                  // 1.6M ints
    float* Wt0      = (float*)((char*)d_ws + 7200256);   // 3 x 32768 floats
    float* Wt1      = Wt0 + 32768;
    float* Wt2      = Wt1 + 32768;
    float* agg      = (float*)((char*)d_ws + 7593472);   // 51.2 MB
    // scan temporaries alias the Wt0 buffer (Wt written strictly later in stream)
    int* bsum       = (int*)Wt0;                         // 98 ints
    int* bpre       = bsum + 128;                        // 98 ints

    const int EB = (N_EDGES + 255) / 256;                // 6250
    const int GB = (N_NODES + TILE_N - 1) / TILE_N;      // 3125
    const int AB = (N_NODES * 64 + 255) / 256;           // 25000 (one wave per node)
    const int TB = (256 * 128 + 255) / 256;              // 128

    // CSR build (once; reused by all 3 layers)
    hipMemsetAsync(cnt, 0, N_NODES * sizeof(int), stream);
    hist_kernel<<<EB, 256, 0, stream>>>(dst, cnt, N_EDGES);
    scan_reduce<<<NBS, 256, 0, stream>>>(cnt, bsum, N_NODES);
    scan_partials<<<1, 128, 0, stream>>>(bsum, bpre);
    scan_write<<<NBS, 1024, 0, stream>>>(cnt, bpre, row_ptr, N_NODES);
    hipMemsetAsync(cnt, 0, N_NODES * sizeof(int), stream);
    scatter_kernel<<<EB, 256, 0, stream>>>(src, dst, row_ptr, cnt, sorted_src, N_EDGES);

    // W transposes (tiny, one-time per call)
    transpose_w<<<TB, 256, 0, stream>>>(Wl0, Wr0, Wt0);
    transpose_w<<<TB, 256, 0, stream>>>(Wl1, Wr1, Wt1);
    transpose_w<<<TB, 256, 0, stream>>>(Wl2, Wr2, Wt2);

    // layer 0: x -> out (ReLU)
    aggregate_kernel<<<AB, 256, 0, stream>>>(x, row_ptr, sorted_src, agg);
    sage_gemm<<<GB, 256, 0, stream>>>(x, agg, Wt0, bl0, out, 1);
    // layer 1: out -> out (ReLU); in-place safe (GEMM row i reads only row i)
    aggregate_kernel<<<AB, 256, 0, stream>>>(out, row_ptr, sorted_src, agg);
    sage_gemm<<<GB, 256, 0, stream>>>(out, agg, Wt1, bl1, out, 1);
    // layer 2: out -> out (no ReLU)
    aggregate_kernel<<<AB, 256, 0, stream>>>(out, row_ptr, sorted_src, agg);
    sage_gemm<<<GB, 256, 0, stream>>>(out, agg, Wt2, bl2, out, 0);
}